// Round 9
// baseline (179.291 us; speedup 1.0000x reference)
//
#include <hip/hip_runtime.h>
#include <hip/hip_bf16.h>

#define N0C 100000
#define N1C 50000
#define N2C 25000

typedef _Float16 f16;
typedef _Float16 f16x2 __attribute__((ext_vector_type(2)));
typedef _Float16 f16x4 __attribute__((ext_vector_type(4)));
typedef _Float16 f16x8 __attribute__((ext_vector_type(8)));
typedef float f32x16 __attribute__((ext_vector_type(16)));

typedef const __attribute__((address_space(1))) unsigned int guint;
typedef __attribute__((address_space(3))) unsigned int luint;
__device__ __forceinline__ void gload16(const void* g, void* l) {
    __builtin_amdgcn_global_load_lds((guint*)g, (luint*)l, 16, 0, 0);
}

__device__ __forceinline__ f16x8 cvt8(float4 a, float4 b) {
    return (f16x8){(f16)a.x, (f16)a.y, (f16)a.z, (f16)a.w,
                   (f16)b.x, (f16)b.y, (f16)b.z, (f16)b.w};
}

// ---------------------------------------------------------------- prep1 -----
__global__ void prep1_kernel(const float* __restrict__ Ws1, const float* __restrict__ Wd1,
                             const float* __restrict__ as1, const float* __restrict__ ad1,
                             const float* __restrict__ Ws2, const float* __restrict__ Wd2,
                             const float* __restrict__ as2, const float* __restrict__ ad2,
                             const float* __restrict__ b1, const float* __restrict__ g1,
                             const float* __restrict__ beta1, const float* __restrict__ m1,
                             const float* __restrict__ v1,
                             float* __restrict__ e1, float* __restrict__ e2,
                             float* __restrict__ bns, float* __restrict__ bnt) {
    int k = blockIdx.x, lane = threadIdx.x;
    float s0 = 0, s1 = 0, d0 = 0, d1 = 0, t0 = 0, t1 = 0;
    for (int c = lane; c < 128; c += 64) {
        s0 += Ws1[k * 256 + c] * as1[c];
        s1 += Ws1[k * 256 + 128 + c] * as1[128 + c];
        d0 += Wd1[k * 256 + c] * ad1[c];
        d1 += Wd1[k * 256 + 128 + c] * ad1[128 + c];
        t0 += Ws2[k * 128 + c] * as2[c];
        t1 += Wd2[k * 128 + c] * ad2[c];
    }
    for (int d = 1; d < 64; d <<= 1) {
        s0 += __shfl_xor(s0, d); s1 += __shfl_xor(s1, d);
        d0 += __shfl_xor(d0, d); d1 += __shfl_xor(d1, d);
        t0 += __shfl_xor(t0, d); t1 += __shfl_xor(t1, d);
    }
    if (lane == 0) {
        e1[k * 4 + 0] = s0; e1[k * 4 + 1] = s1; e1[k * 4 + 2] = d0; e1[k * 4 + 3] = d1;
        e2[k * 2 + 0] = t0; e2[k * 2 + 1] = t1;
        float sc = g1[k] * rsqrtf(v1[k] + 1e-5f);
        bns[k] = sc;
        bnt[k] = (b1[k] - m1[k]) * sc + beta1[k];
    }
}

// ---------------------------------------------------------------- prep2 -----
// bfl1: [9 nt][16 kb][64 lane][8 j]; bfl2: [5 nt][16 kb][64 lane][8 j]
// element (nt,kb,lane,j): n = nt*32 + (lane&31), k = kb*16 + (lane>>5)*8 + j
__global__ void prep2_kernel(const float* __restrict__ Ws1, const float* __restrict__ Ws2,
                             const float* __restrict__ e1, const float* __restrict__ e2,
                             f16* __restrict__ bfl1, f16* __restrict__ bfl2) {
    int i = blockIdx.x * 256 + threadIdx.x;
    if (i < 73728) {
        int j = i & 7, lane = (i >> 3) & 63, kb = (i >> 9) & 15, nt = i >> 13;
        int c = lane & 31, hi = lane >> 5;
        int k = kb * 16 + hi * 8 + j;
        float v;
        if (nt < 8) v = Ws1[k * 256 + nt * 32 + c];
        else v = (c < 4) ? e1[k * 4 + c] : 0.f;
        bfl1[i] = (f16)v;
    } else {
        int i2 = i - 73728;
        if (i2 < 40960) {
            int j = i2 & 7, lane = (i2 >> 3) & 63, kb = (i2 >> 9) & 15, nt = i2 >> 13;
            int c = lane & 31, hi = lane >> 5;
            int k = kb * 16 + hi * 8 + j;
            float v;
            if (nt < 4) v = Ws2[k * 128 + nt * 32 + c];
            else v = (c < 2) ? e2[k * 2 + c] : 0.f;
            bfl2[i2] = (f16)v;
        }
    }
}

// ---------------------------------------------------------------- gemm1 -----
// Persistent blocks: 512 blocks (2/CU) x 8 waves; wave w = nt w, B frags
// loaded ONCE per block (64 VGPR, tile-invariant). Wave 0 also accumulates
// the attention pad tile (nt 8) from LDS smP. Each block loops ~6 tiles of
// 32 rows with 1-deep pipeline: issue x loads(t+1) -> MFMA(t) -> stores(t)
// -> cvt+ds_write(t+1) -> syncthreads. x read exactly once; 3125 tiles exact.
__global__ __launch_bounds__(512, 4) void gemm1_kernel(
    const float* __restrict__ x, const f16* __restrict__ bfl,
    f16* __restrict__ hs, float* __restrict__ as_out, float* __restrict__ ad_out) {
    __shared__ __align__(16) unsigned char smA[2][16384];
    __shared__ __align__(16) unsigned char smP[16384];
    const int t = threadIdx.x;
    const int wave = t >> 6, lane = t & 63;
    const int col = lane & 31, hi = lane >> 5;
    const int nt = wave;

    // persistent B fragments for this wave's nt
    f16x8 b[16];
#pragma unroll
    for (int kb = 0; kb < 16; kb++)
        b[kb] = *(const f16x8*)(bfl + ((size_t)(nt * 16 + kb) * 64 + lane) * 8);

    // pad-tile B (nt=8) -> smP via global_load_lds (2 chunks/wave)
    {
        int c0 = wave * 2;
        gload16(bfl + ((size_t)(8 * 16 + c0) * 64 + lane) * 8, smP + (c0 * 64 + lane) * 16);
        gload16(bfl + ((size_t)(8 * 16 + c0 + 1) * 64 + lane) * 8, smP + ((c0 + 1) * 64 + lane) * 16);
    }

    // A staging map: thread -> (row srow, 64B segment sseg) of a 32x256 tile
    const int srow = t >> 4, sseg = t & 15;
    const int c2 = sseg * 2, r7s = srow & 7;
    const int t0 = blockIdx.x;
    // stage tile t0
    {
        const float4* p = (const float4*)(x + ((size_t)t0 * 32 + srow) * 256 + sseg * 16);
        float4 a0 = p[0], a1 = p[1], a2 = p[2], a3 = p[3];
        unsigned char* wb = smA[0] + srow * 512;
        *(f16x8*)(wb + ((c2 ^ r7s) * 16)) = cvt8(a0, a1);
        *(f16x8*)(wb + (((c2 + 1) ^ r7s) * 16)) = cvt8(a2, a3);
    }
    __syncthreads();

    int cur = 0;
    for (int tt = t0; tt < 3125; tt += 512) {
        const bool pre = (tt + 512) < 3125;
        float4 a0, a1, a2, a3;
        if (pre) {  // issue next tile's loads; fly under MFMA + stores
            const float4* p = (const float4*)(x + ((size_t)(tt + 512) * 32 + srow) * 256 + sseg * 16);
            a0 = p[0]; a1 = p[1]; a2 = p[2]; a3 = p[3];
        }
        const unsigned char* buf = smA[cur];
        const int r0 = tt * 32;
        if (wave == 0) {
            f32x16 acc = {}, accp = {};
#pragma unroll
            for (int kb = 0; kb < 16; kb++) {
                f16x8 af = *(const f16x8*)(buf + col * 512 + (((2 * kb + hi) ^ (col & 7)) * 16));
                f16x8 bp = *(const f16x8*)(smP + (kb * 64 + lane) * 16);
                acc = __builtin_amdgcn_mfma_f32_32x32x16_f16(af, b[kb], acc, 0, 0, 0);
                accp = __builtin_amdgcn_mfma_f32_32x32x16_f16(af, bp, accp, 0, 0, 0);
            }
#pragma unroll
            for (int r = 0; r < 16; r++) {
                int grow = r0 + (r & 3) + 8 * (r >> 2) + 4 * hi;
                hs[(size_t)grow * 256 + col] = (f16)acc[r];
                float v = accp[r];
                if (col < 2) {
                    as_out[grow * 2 + col] = v;
                } else if (col < 4) {
                    if (grow < N1C) ad_out[grow * 2 + (col - 2)] = v;
                }
            }
        } else {
            f32x16 acc = {};
#pragma unroll
            for (int kb = 0; kb < 16; kb++) {
                f16x8 af = *(const f16x8*)(buf + col * 512 + (((2 * kb + hi) ^ (col & 7)) * 16));
                acc = __builtin_amdgcn_mfma_f32_32x32x16_f16(af, b[kb], acc, 0, 0, 0);
            }
#pragma unroll
            for (int r = 0; r < 16; r++) {
                int grow = r0 + (r & 3) + 8 * (r >> 2) + 4 * hi;
                hs[(size_t)grow * 256 + nt * 32 + col] = (f16)acc[r];
            }
        }
        if (pre) {  // convert + write next tile into the other buffer
            unsigned char* wb = smA[cur ^ 1] + srow * 512;
            *(f16x8*)(wb + ((c2 ^ r7s) * 16)) = cvt8(a0, a1);
            *(f16x8*)(wb + (((c2 + 1) ^ r7s) * 16)) = cvt8(a2, a3);
        }
        __syncthreads();
        cur ^= 1;
    }
}

// ---------------------------------------------------------------- gemm2 -----
// K-split skeleton (R8): block = 640 thr (5 nt x 2 khalf), 32 rows, nt4 = pad.
// A (f16) staged via global_load_lds, inverse-swizzled per-lane SOURCE.
__global__ __launch_bounds__(640, 8) void gemm2_kernel(
    const f16* __restrict__ h, const f16* __restrict__ bfl,
    f16* __restrict__ hs2, float* __restrict__ as_out, float* __restrict__ ad_out) {
    __shared__ __align__(16) unsigned char smA[20480];
    const int t = threadIdx.x;
    const int wave = t >> 6, lane = t & 63;
    const int ntl = wave >> 1, khalf = wave & 1;
    const int col = lane & 31, hi = lane >> 5;
    const int r0 = blockIdx.x * 32;

    if (t < 256) {
#pragma unroll
        for (int p = 0; p < 4; p++) {
            int i = p * 256 + t;                  // 16B-slot index 0..1023
            int row = i >> 5, s = i & 31;
            int grow = r0 + row;
            if (grow > N1C - 1) grow = N1C - 1;
            const f16* src = h + (size_t)grow * 256 + ((s ^ (row & 7)) * 8);
            gload16(src, smA + p * 4096 + (t >> 6) * 1024 + (lane << 4));
        }
    }
    f16x8 b[8];
#pragma unroll
    for (int i = 0; i < 8; i++)
        b[i] = *(const f16x8*)(bfl + ((size_t)(ntl * 16 + khalf * 8 + i) * 64 + lane) * 8);

    __syncthreads();
    const int r7 = col & 7;
    f32x16 acc = {};
#pragma unroll
    for (int i = 0; i < 8; i++) {
        int kb = khalf * 8 + i;
        int sl = (2 * kb + hi) ^ r7;
        f16x8 af = *(const f16x8*)(smA + col * 512 + sl * 16);
        acc = __builtin_amdgcn_mfma_f32_32x32x16_f16(af, b[i], acc, 0, 0, 0);
    }
    __syncthreads();
    if (khalf == 1) {
        float* rb = (float*)(smA + ntl * 4096) + lane * 16;
#pragma unroll
        for (int r = 0; r < 16; r++) rb[r] = acc[r];
    }
    __syncthreads();
    if (khalf == 0) {
        const float* rb = (const float*)(smA + ntl * 4096) + lane * 16;
        if (ntl < 4) {
#pragma unroll
            for (int r = 0; r < 16; r++) {
                int grow = r0 + (r & 3) + 8 * (r >> 2) + 4 * hi;
                if (grow < N1C) hs2[(size_t)grow * 128 + ntl * 32 + col] = (f16)(acc[r] + rb[r]);
            }
        } else {
#pragma unroll
            for (int r = 0; r < 16; r++) {
                int grow = r0 + (r & 3) + 8 * (r >> 2) + 4 * hi;
                float v = acc[r] + rb[r];
                if (col == 0) {
                    if (grow < N1C) as_out[grow] = v;
                } else if (col == 1) {
                    if (grow < N2C) ad_out[grow] = v;
                }
            }
        }
    }
}

// ---------------------------------------------------------------- agg1 ------
__global__ void agg1_kernel(const int* __restrict__ col1, const int* __restrict__ t1,
                            const int* __restrict__ timep, const int* __restrict__ intervalp,
                            const float* __restrict__ a_s, const float* __restrict__ a_d,
                            const f16* __restrict__ hs,
                            const float* __restrict__ bns, const float* __restrict__ bnt,
                            f16* __restrict__ h) {
    int wid = (blockIdx.x * blockDim.x + threadIdx.x) >> 6;
    if (wid >= N1C) return;
    int lane = threadIdx.x & 63;
    int T = timep[0], I = intervalp[0];
    int j = lane & 15;
    int c = col1[wid * 16 + j];
    int tv = t1[wid * 16 + j];
    bool mk = (tv >= T) && (tv < T + I);
    float e0 = -INFINITY, e1 = -INFINITY;
    if (mk) {
        float s0 = a_s[c * 2 + 0] + a_d[wid * 2 + 0];
        float s1 = a_s[c * 2 + 1] + a_d[wid * 2 + 1];
        e0 = s0 > 0.f ? s0 : 0.2f * s0;
        e1 = s1 > 0.f ? s1 : 0.2f * s1;
    }
    float m0 = e0, m1 = e1;
#pragma unroll
    for (int d = 1; d < 16; d <<= 1) {
        m0 = fmaxf(m0, __shfl_xor(m0, d));
        m1 = fmaxf(m1, __shfl_xor(m1, d));
    }
    float ex0 = mk ? __expf(e0 - m0) : 0.f;
    float ex1 = mk ? __expf(e1 - m1) : 0.f;
    float s0 = ex0, s1 = ex1;
#pragma unroll
    for (int d = 1; d < 16; d <<= 1) {
        s0 += __shfl_xor(s0, d);
        s1 += __shfl_xor(s1, d);
    }
    float r0 = 1.f / fmaxf(s0, 1e-16f);
    float r1 = 1.f / fmaxf(s1, 1e-16f);
    unsigned long long mb = __ballot(mk) & 0xFFFFull;
    int head = lane >> 5;
    float rden = head ? r1 : r0;
    float acc0 = 0.f, acc1 = 0.f, acc2 = 0.f, acc3 = 0.f;
    while (mb) {
        int jj = __builtin_ctzll(mb);
        mb &= mb - 1;
        int cj = __shfl(c, jj);
        float w0 = __shfl(ex0, jj), w1 = __shfl(ex1, jj);
        float w = (head ? w1 : w0) * rden;
        f16x4 v = *(const f16x4*)(hs + (size_t)cj * 256 + lane * 4);
        acc0 += w * (float)v[0];
        acc1 += w * (float)v[1];
        acc2 += w * (float)v[2];
        acc3 += w * (float)v[3];
    }
    int cb = lane * 4;
    float4 sc = *(const float4*)(bns + cb);
    float4 sh = *(const float4*)(bnt + cb);
    float o0 = acc0 * sc.x + sh.x; o0 = o0 > 0.f ? o0 : 0.01f * o0;
    float o1 = acc1 * sc.y + sh.y; o1 = o1 > 0.f ? o1 : 0.01f * o1;
    float o2 = acc2 * sc.z + sh.z; o2 = o2 > 0.f ? o2 : 0.01f * o2;
    float o3 = acc3 * sc.w + sh.w; o3 = o3 > 0.f ? o3 : 0.01f * o3;
    f16x4 ov = {(f16)o0, (f16)o1, (f16)o2, (f16)o3};
    *(f16x4*)(h + (size_t)wid * 256 + cb) = ov;
}

// ---------------------------------------------------------------- agg2 ------
__global__ void agg2_kernel(const int* __restrict__ col2, const int* __restrict__ t2,
                            const int* __restrict__ timep, const int* __restrict__ intervalp,
                            const float* __restrict__ a_s, const float* __restrict__ a_d,
                            const f16* __restrict__ hs2,
                            const float* __restrict__ b2, float* __restrict__ out) {
    int wid = (blockIdx.x * blockDim.x + threadIdx.x) >> 6;
    if (wid >= N2C) return;
    int lane = threadIdx.x & 63;
    int T = timep[0], I = intervalp[0];
    int j = lane & 15;
    int c = col2[wid * 16 + j];
    int tv = t2[wid * 16 + j];
    bool mk = (tv >= T) && (tv < T + I);
    float e = -INFINITY;
    if (mk) {
        float s = a_s[c] + a_d[wid];
        e = s > 0.f ? s : 0.2f * s;
    }
    float m = e;
#pragma unroll
    for (int d = 1; d < 16; d <<= 1) m = fmaxf(m, __shfl_xor(m, d));
    float ex = mk ? __expf(e - m) : 0.f;
    float s = ex;
#pragma unroll
    for (int d = 1; d < 16; d <<= 1) s += __shfl_xor(s, d);
    float r = 1.f / fmaxf(s, 1e-16f);
    unsigned long long mb = __ballot(mk) & 0xFFFFull;
    float acc0 = 0.f, acc1 = 0.f;
    while (mb) {
        int jj = __builtin_ctzll(mb);
        mb &= mb - 1;
        int cj = __shfl(c, jj);
        float w = __shfl(ex, jj) * r;
        f16x2 v = *(const f16x2*)(hs2 + (size_t)cj * 128 + lane * 2);
        acc0 += w * (float)v[0];
        acc1 += w * (float)v[1];
    }
    float2 o = make_float2(acc0 + b2[lane * 2], acc1 + b2[lane * 2 + 1]);
    *(float2*)(out + (size_t)wid * 128 + lane * 2) = o;
}

// ---------------------------------------------------------------- launch ----
extern "C" void kernel_launch(void* const* d_in, const int* in_sizes, int n_in,
                              void* d_out, int out_size, void* d_ws, size_t ws_size,
                              hipStream_t stream) {
    const float* x = (const float*)d_in[0];
    const int* col1 = (const int*)d_in[2];
    const int* t1 = (const int*)d_in[3];
    const int* col2 = (const int*)d_in[5];
    const int* t2 = (const int*)d_in[6];
    const int* timep = (const int*)d_in[7];
    const int* intervalp = (const int*)d_in[8];
    const float* Ws1 = (const float*)d_in[9];
    const float* Wd1 = (const float*)d_in[10];
    const float* as1 = (const float*)d_in[11];
    const float* ad1 = (const float*)d_in[12];
    const float* b1 = (const float*)d_in[13];
    const float* g1 = (const float*)d_in[14];
    const float* beta1 = (const float*)d_in[15];
    const float* m1 = (const float*)d_in[16];
    const float* v1 = (const float*)d_in[17];
    const float* Ws2 = (const float*)d_in[18];
    const float* Wd2 = (const float*)d_in[19];
    const float* as2 = (const float*)d_in[20];
    const float* ad2 = (const float*)d_in[21];
    const float* b2 = (const float*)d_in[22];
    float* out = (float*)d_out;

    char* ws = (char*)d_ws;
    size_t off = 0;
    auto alloc = [&](size_t bytes) {
        size_t o = off;
        off += (bytes + 511) & ~(size_t)511;
        return o;
    };
    f16* hs = (f16*)(ws + alloc((size_t)N0C * 256 * 2));
    f16* h = (f16*)(ws + alloc((size_t)N1C * 256 * 2));
    f16* hs2 = (f16*)(ws + alloc((size_t)N1C * 128 * 2));
    float* a_s1 = (float*)(ws + alloc((size_t)N0C * 2 * 4));
    float* a_d1 = (float*)(ws + alloc((size_t)N1C * 2 * 4));
    float* a_s2 = (float*)(ws + alloc((size_t)N1C * 4));
    float* a_d2 = (float*)(ws + alloc((size_t)N2C * 4));
    f16* bfl1 = (f16*)(ws + alloc((size_t)73728 * 2));
    f16* bfl2 = (f16*)(ws + alloc((size_t)40960 * 2));
    float* e1 = (float*)(ws + alloc(1024 * 4));
    float* e2 = (float*)(ws + alloc(512 * 4));
    float* bns = (float*)(ws + alloc(256 * 4));
    float* bnt = (float*)(ws + alloc(256 * 4));

    prep1_kernel<<<256, 64, 0, stream>>>(Ws1, Wd1, as1, ad1, Ws2, Wd2, as2, ad2,
                                         b1, g1, beta1, m1, v1, e1, e2, bns, bnt);
    prep2_kernel<<<448, 256, 0, stream>>>(Ws1, Ws2, e1, e2, bfl1, bfl2);
    gemm1_kernel<<<512, 512, 0, stream>>>(x, bfl1, hs, a_s1, a_d1);
    agg1_kernel<<<N1C / 4, 256, 0, stream>>>(col1, t1, timep, intervalp,
                                             a_s1, a_d1, hs, bns, bnt, h);
    gemm2_kernel<<<(N1C + 31) / 32, 640, 0, stream>>>(h, bfl2, hs2, a_s2, a_d2);
    agg2_kernel<<<N2C / 4, 256, 0, stream>>>(col2, t2, timep, intervalp,
                                             a_s2, a_d2, hs2, b2, out);
}

// Round 10
// 103.724 us; speedup vs baseline: 1.7285x; 1.7285x over previous
//
#include <hip/hip_runtime.h>
#include <hip/hip_bf16.h>

#define N0C 100000
#define N1C 50000
#define N2C 25000

typedef _Float16 f16;
typedef _Float16 f16x2 __attribute__((ext_vector_type(2)));
typedef _Float16 f16x4 __attribute__((ext_vector_type(4)));
typedef _Float16 f16x8 __attribute__((ext_vector_type(8)));
typedef float f32x16 __attribute__((ext_vector_type(16)));

typedef const __attribute__((address_space(1))) unsigned int guint;
typedef __attribute__((address_space(3))) unsigned int luint;
__device__ __forceinline__ void gload16(const void* g, void* l) {
    __builtin_amdgcn_global_load_lds((guint*)g, (luint*)l, 16, 0, 0);
}

__device__ __forceinline__ f16x8 cvt8(float4 a, float4 b) {
    return (f16x8){(f16)a.x, (f16)a.y, (f16)a.z, (f16)a.w,
                   (f16)b.x, (f16)b.y, (f16)b.z, (f16)b.w};
}

// ---------------------------------------------------------------- prep1 -----
__global__ void prep1_kernel(const float* __restrict__ Ws1, const float* __restrict__ Wd1,
                             const float* __restrict__ as1, const float* __restrict__ ad1,
                             const float* __restrict__ Ws2, const float* __restrict__ Wd2,
                             const float* __restrict__ as2, const float* __restrict__ ad2,
                             const float* __restrict__ b1, const float* __restrict__ g1,
                             const float* __restrict__ beta1, const float* __restrict__ m1,
                             const float* __restrict__ v1,
                             float* __restrict__ e1, float* __restrict__ e2,
                             float* __restrict__ bns, float* __restrict__ bnt) {
    int k = blockIdx.x, lane = threadIdx.x;
    float s0 = 0, s1 = 0, d0 = 0, d1 = 0, t0 = 0, t1 = 0;
    for (int c = lane; c < 128; c += 64) {
        s0 += Ws1[k * 256 + c] * as1[c];
        s1 += Ws1[k * 256 + 128 + c] * as1[128 + c];
        d0 += Wd1[k * 256 + c] * ad1[c];
        d1 += Wd1[k * 256 + 128 + c] * ad1[128 + c];
        t0 += Ws2[k * 128 + c] * as2[c];
        t1 += Wd2[k * 128 + c] * ad2[c];
    }
    for (int d = 1; d < 64; d <<= 1) {
        s0 += __shfl_xor(s0, d); s1 += __shfl_xor(s1, d);
        d0 += __shfl_xor(d0, d); d1 += __shfl_xor(d1, d);
        t0 += __shfl_xor(t0, d); t1 += __shfl_xor(t1, d);
    }
    if (lane == 0) {
        e1[k * 4 + 0] = s0; e1[k * 4 + 1] = s1; e1[k * 4 + 2] = d0; e1[k * 4 + 3] = d1;
        e2[k * 2 + 0] = t0; e2[k * 2 + 1] = t1;
        float sc = g1[k] * rsqrtf(v1[k] + 1e-5f);
        bns[k] = sc;
        bnt[k] = (b1[k] - m1[k]) * sc + beta1[k];
    }
}

// ---------------------------------------------------------------- prep2 -----
// bfl1: [9 nt][16 kb][64 lane][8 j]; bfl2: [5 nt][16 kb][64 lane][8 j]
// element (nt,kb,lane,j): n = nt*32 + (lane&31), k = kb*16 + (lane>>5)*8 + j
__global__ void prep2_kernel(const float* __restrict__ Ws1, const float* __restrict__ Ws2,
                             const float* __restrict__ e1, const float* __restrict__ e2,
                             f16* __restrict__ bfl1, f16* __restrict__ bfl2) {
    int i = blockIdx.x * 256 + threadIdx.x;
    if (i < 73728) {
        int j = i & 7, lane = (i >> 3) & 63, kb = (i >> 9) & 15, nt = i >> 13;
        int c = lane & 31, hi = lane >> 5;
        int k = kb * 16 + hi * 8 + j;
        float v;
        if (nt < 8) v = Ws1[k * 256 + nt * 32 + c];
        else v = (c < 4) ? e1[k * 4 + c] : 0.f;
        bfl1[i] = (f16)v;
    } else {
        int i2 = i - 73728;
        if (i2 < 40960) {
            int j = i2 & 7, lane = (i2 >> 3) & 63, kb = (i2 >> 9) & 15, nt = i2 >> 13;
            int c = lane & 31, hi = lane >> 5;
            int k = kb * 16 + hi * 8 + j;
            float v;
            if (nt < 4) v = Ws2[k * 128 + nt * 32 + c];
            else v = (c < 2) ? e2[k * 2 + c] : 0.f;
            bfl2[i2] = (f16)v;
        }
    }
}

// ---------------------------------------------------------------- gemm1 -----
// 2-phase pipelined tile GEMM (catalog T3-lite). BM=128, BK=32, 8 K-steps,
// 8 waves = 4 row-tiles x 2 col-groups (nt0-4 / nt5-8, nt8 = attention pad).
// Per step: issue A-reg loads (ch+1) FIRST, then 18 B global_load_lds (ch+1)
// -> dbuf; compute step ch from LDS; cvt+ds_write A(ch+1); ONE barrier.
// B loads span the compute phase (counted-vmcnt effect, no inline asm).
// All LDS fragment-linear: every ds_read/write is consecutive-lane 16B.
__global__ __launch_bounds__(512, 4) void gemm1_kernel(
    const float* __restrict__ x, const f16* __restrict__ bfl,
    f16* __restrict__ hs, float* __restrict__ as_out, float* __restrict__ ad_out) {
    __shared__ __align__(16) unsigned char smA[2][8192];
    __shared__ __align__(16) unsigned char smB[2][18432];
    const int t = threadIdx.x;
    const int wave = t >> 6, lane = t & 63;
    const int wr = wave & 3, wg = wave >> 2;
    const int col = lane & 31, hi = lane >> 5;
    const int r0 = blockIdx.x * 128;

    // A stage map: thread t -> row arow, k-octet aq (8 floats = one frag half)
    const int arow = t >> 2, aq = t & 3;
    const int grow_a = r0 + arow;
    const bool aval = grow_a < N0C;
    const float4* abase = (const float4*)(x + (size_t)grow_a * 256);
    const int aslot = (((arow >> 5) * 2 + (aq >> 1)) * 64 + (aq & 1) * 32 + (arow & 31)) * 16;

    // prologue: A(0) regs first, then B(0) gloads, then cvt+write, barrier
    float4 a0, a1;
    if (aval) { a0 = abase[aq * 2]; a1 = abase[aq * 2 + 1]; }
    else { a0 = make_float4(0.f, 0.f, 0.f, 0.f); a1 = a0; }
    for (int c = wave; c < 18; c += 8) {
        int nt = c >> 1, kbl = c & 1;
        gload16(bfl + ((size_t)(nt * 16 + kbl) * 64 + lane) * 8, smB[0] + c * 1024 + lane * 16);
    }
    *(f16x8*)(smA[0] + aslot) = cvt8(a0, a1);
    __syncthreads();

    f32x16 acc[5] = {};
    for (int ch = 0; ch < 8; ch++) {
        const int cur = ch & 1, nxt = cur ^ 1;
        const bool pre = ch < 7;
        if (pre) {
            if (aval) {
                const float4* p = abase + (ch + 1) * 8 + aq * 2;
                a0 = p[0]; a1 = p[1];
            }
            for (int c = wave; c < 18; c += 8) {
                int nt = c >> 1, kbl = c & 1;
                gload16(bfl + ((size_t)(nt * 16 + (ch + 1) * 2 + kbl) * 64 + lane) * 8,
                        smB[nxt] + c * 1024 + lane * 16);
            }
        }
#pragma unroll
        for (int kb = 0; kb < 2; kb++) {
            f16x8 af = *(const f16x8*)(smA[cur] + ((wr * 2 + kb) * 64 + lane) * 16);
            if (wg == 0) {
#pragma unroll
                for (int j = 0; j < 5; j++) {
                    f16x8 bf = *(const f16x8*)(smB[cur] + (j * 2 + kb) * 1024 + lane * 16);
                    acc[j] = __builtin_amdgcn_mfma_f32_32x32x16_f16(af, bf, acc[j], 0, 0, 0);
                }
            } else {
#pragma unroll
                for (int j = 0; j < 4; j++) {
                    f16x8 bf = *(const f16x8*)(smB[cur] + ((5 + j) * 2 + kb) * 1024 + lane * 16);
                    acc[j] = __builtin_amdgcn_mfma_f32_32x32x16_f16(af, bf, acc[j], 0, 0, 0);
                }
            }
        }
        if (pre) *(f16x8*)(smA[nxt] + aslot) = cvt8(a0, a1);
        __syncthreads();
    }

    // epilogue: C/D layout col=lane&31, row=(r&3)+8*(r>>2)+4*hi
    const int rbase = r0 + wr * 32 + 4 * hi;
    if (wg == 0) {
#pragma unroll
        for (int j = 0; j < 5; j++)
#pragma unroll
            for (int r = 0; r < 16; r++) {
                int grow = rbase + (r & 3) + 8 * (r >> 2);
                if (grow < N0C) hs[(size_t)grow * 256 + j * 32 + col] = (f16)acc[j][r];
            }
    } else {
#pragma unroll
        for (int j = 0; j < 3; j++)
#pragma unroll
            for (int r = 0; r < 16; r++) {
                int grow = rbase + (r & 3) + 8 * (r >> 2);
                if (grow < N0C) hs[(size_t)grow * 256 + (5 + j) * 32 + col] = (f16)acc[j][r];
            }
#pragma unroll
        for (int r = 0; r < 16; r++) {
            int grow = rbase + (r & 3) + 8 * (r >> 2);
            float v = acc[3][r];
            if (col < 2) {
                if (grow < N0C) as_out[grow * 2 + col] = v;
            } else if (col < 4) {
                if (grow < N1C) ad_out[grow * 2 + (col - 2)] = v;
            }
        }
    }
}

// ---------------------------------------------------------------- gemm2 -----
// Same 2-phase skeleton. A (f16) staged via global_load_lds with per-lane
// fragment-linear SOURCE (linear LDS dest + linear read). 8 A-chunks +
// 10 B-chunks per step; col-groups nt0-2 / nt3-4 (nt4 = pad).
__global__ __launch_bounds__(512, 4) void gemm2_kernel(
    const f16* __restrict__ h, const f16* __restrict__ bfl,
    f16* __restrict__ hs2, float* __restrict__ as_out, float* __restrict__ ad_out) {
    __shared__ __align__(16) unsigned char smA[2][8192];
    __shared__ __align__(16) unsigned char smB[2][10240];
    const int t = threadIdx.x;
    const int wave = t >> 6, lane = t & 63;
    const int wr = wave & 3, wg = wave >> 2;
    const int col = lane & 31, hi = lane >> 5;
    const int r0 = blockIdx.x * 128;

    // A chunk for this wave: cA = wave (wrA = wave>>1, kb = wave&1)
    const int wrA = wave >> 1, kbA = wave & 1;
    int arowg = r0 + wrA * 32 + col;
    if (arowg > N1C - 1) arowg = N1C - 1;
    const f16* asrc = h + (size_t)arowg * 256 + kbA * 16 + hi * 8;

    // prologue
    gload16(asrc, smA[0] + wave * 1024 + lane * 16);
    for (int c = wave; c < 10; c += 8) {
        int nt = c >> 1, kbl = c & 1;
        gload16(bfl + ((size_t)(nt * 16 + kbl) * 64 + lane) * 8, smB[0] + c * 1024 + lane * 16);
    }
    __syncthreads();

    f32x16 acc[3] = {};
    for (int ch = 0; ch < 8; ch++) {
        const int cur = ch & 1, nxt = cur ^ 1;
        const bool pre = ch < 7;
        if (pre) {
            gload16(asrc + (ch + 1) * 32, smA[nxt] + wave * 1024 + lane * 16);
            for (int c = wave; c < 10; c += 8) {
                int nt = c >> 1, kbl = c & 1;
                gload16(bfl + ((size_t)(nt * 16 + (ch + 1) * 2 + kbl) * 64 + lane) * 8,
                        smB[nxt] + c * 1024 + lane * 16);
            }
        }
#pragma unroll
        for (int kb = 0; kb < 2; kb++) {
            f16x8 af = *(const f16x8*)(smA[cur] + ((wr * 2 + kb) * 64 + lane) * 16);
            if (wg == 0) {
#pragma unroll
                for (int j = 0; j < 3; j++) {
                    f16x8 bf = *(const f16x8*)(smB[cur] + (j * 2 + kb) * 1024 + lane * 16);
                    acc[j] = __builtin_amdgcn_mfma_f32_32x32x16_f16(af, bf, acc[j], 0, 0, 0);
                }
            } else {
#pragma unroll
                for (int j = 0; j < 2; j++) {
                    f16x8 bf = *(const f16x8*)(smB[cur] + ((3 + j) * 2 + kb) * 1024 + lane * 16);
                    acc[j] = __builtin_amdgcn_mfma_f32_32x32x16_f16(af, bf, acc[j], 0, 0, 0);
                }
            }
        }
        __syncthreads();
    }

    const int rbase = r0 + wr * 32 + 4 * hi;
    if (wg == 0) {
#pragma unroll
        for (int j = 0; j < 3; j++)
#pragma unroll
            for (int r = 0; r < 16; r++) {
                int grow = rbase + (r & 3) + 8 * (r >> 2);
                if (grow < N1C) hs2[(size_t)grow * 128 + j * 32 + col] = (f16)acc[j][r];
            }
    } else {
#pragma unroll
        for (int r = 0; r < 16; r++) {
            int grow = rbase + (r & 3) + 8 * (r >> 2);
            if (grow < N1C) hs2[(size_t)grow * 128 + 3 * 32 + col] = (f16)acc[0][r];
        }
#pragma unroll
        for (int r = 0; r < 16; r++) {
            int grow = rbase + (r & 3) + 8 * (r >> 2);
            float v = acc[1][r];
            if (col == 0) {
                if (grow < N1C) as_out[grow] = v;
            } else if (col == 1) {
                if (grow < N2C) ad_out[grow] = v;
            }
        }
    }
}

// ---------------------------------------------------------------- agg1 ------
__global__ void agg1_kernel(const int* __restrict__ col1, const int* __restrict__ t1,
                            const int* __restrict__ timep, const int* __restrict__ intervalp,
                            const float* __restrict__ a_s, const float* __restrict__ a_d,
                            const f16* __restrict__ hs,
                            const float* __restrict__ bns, const float* __restrict__ bnt,
                            f16* __restrict__ h) {
    int wid = (blockIdx.x * blockDim.x + threadIdx.x) >> 6;
    if (wid >= N1C) return;
    int lane = threadIdx.x & 63;
    int T = timep[0], I = intervalp[0];
    int j = lane & 15;
    int c = col1[wid * 16 + j];
    int tv = t1[wid * 16 + j];
    bool mk = (tv >= T) && (tv < T + I);
    float e0 = -INFINITY, e1 = -INFINITY;
    if (mk) {
        float s0 = a_s[c * 2 + 0] + a_d[wid * 2 + 0];
        float s1 = a_s[c * 2 + 1] + a_d[wid * 2 + 1];
        e0 = s0 > 0.f ? s0 : 0.2f * s0;
        e1 = s1 > 0.f ? s1 : 0.2f * s1;
    }
    float m0 = e0, m1 = e1;
#pragma unroll
    for (int d = 1; d < 16; d <<= 1) {
        m0 = fmaxf(m0, __shfl_xor(m0, d));
        m1 = fmaxf(m1, __shfl_xor(m1, d));
    }
    float ex0 = mk ? __expf(e0 - m0) : 0.f;
    float ex1 = mk ? __expf(e1 - m1) : 0.f;
    float s0 = ex0, s1 = ex1;
#pragma unroll
    for (int d = 1; d < 16; d <<= 1) {
        s0 += __shfl_xor(s0, d);
        s1 += __shfl_xor(s1, d);
    }
    float r0 = 1.f / fmaxf(s0, 1e-16f);
    float r1 = 1.f / fmaxf(s1, 1e-16f);
    unsigned long long mb = __ballot(mk) & 0xFFFFull;
    int head = lane >> 5;
    float rden = head ? r1 : r0;
    float acc0 = 0.f, acc1 = 0.f, acc2 = 0.f, acc3 = 0.f;
    while (mb) {
        int jj = __builtin_ctzll(mb);
        mb &= mb - 1;
        int cj = __shfl(c, jj);
        float w0 = __shfl(ex0, jj), w1 = __shfl(ex1, jj);
        float w = (head ? w1 : w0) * rden;
        f16x4 v = *(const f16x4*)(hs + (size_t)cj * 256 + lane * 4);
        acc0 += w * (float)v[0];
        acc1 += w * (float)v[1];
        acc2 += w * (float)v[2];
        acc3 += w * (float)v[3];
    }
    int cb = lane * 4;
    float4 sc = *(const float4*)(bns + cb);
    float4 sh = *(const float4*)(bnt + cb);
    float o0 = acc0 * sc.x + sh.x; o0 = o0 > 0.f ? o0 : 0.01f * o0;
    float o1 = acc1 * sc.y + sh.y; o1 = o1 > 0.f ? o1 : 0.01f * o1;
    float o2 = acc2 * sc.z + sh.z; o2 = o2 > 0.f ? o2 : 0.01f * o2;
    float o3 = acc3 * sc.w + sh.w; o3 = o3 > 0.f ? o3 : 0.01f * o3;
    f16x4 ov = {(f16)o0, (f16)o1, (f16)o2, (f16)o3};
    *(f16x4*)(h + (size_t)wid * 256 + cb) = ov;
}

// ---------------------------------------------------------------- agg2 ------
__global__ void agg2_kernel(const int* __restrict__ col2, const int* __restrict__ t2,
                            const int* __restrict__ timep, const int* __restrict__ intervalp,
                            const float* __restrict__ a_s, const float* __restrict__ a_d,
                            const f16* __restrict__ hs2,
                            const float* __restrict__ b2, float* __restrict__ out) {
    int wid = (blockIdx.x * blockDim.x + threadIdx.x) >> 6;
    if (wid >= N2C) return;
    int lane = threadIdx.x & 63;
    int T = timep[0], I = intervalp[0];
    int j = lane & 15;
    int c = col2[wid * 16 + j];
    int tv = t2[wid * 16 + j];
    bool mk = (tv >= T) && (tv < T + I);
    float e = -INFINITY;
    if (mk) {
        float s = a_s[c] + a_d[wid];
        e = s > 0.f ? s : 0.2f * s;
    }
    float m = e;
#pragma unroll
    for (int d = 1; d < 16; d <<= 1) m = fmaxf(m, __shfl_xor(m, d));
    float ex = mk ? __expf(e - m) : 0.f;
    float s = ex;
#pragma unroll
    for (int d = 1; d < 16; d <<= 1) s += __shfl_xor(s, d);
    float r = 1.f / fmaxf(s, 1e-16f);
    unsigned long long mb = __ballot(mk) & 0xFFFFull;
    float acc0 = 0.f, acc1 = 0.f;
    while (mb) {
        int jj = __builtin_ctzll(mb);
        mb &= mb - 1;
        int cj = __shfl(c, jj);
        float w = __shfl(ex, jj) * r;
        f16x2 v = *(const f16x2*)(hs2 + (size_t)cj * 128 + lane * 2);
        acc0 += w * (float)v[0];
        acc1 += w * (float)v[1];
    }
    float2 o = make_float2(acc0 + b2[lane * 2], acc1 + b2[lane * 2 + 1]);
    *(float2*)(out + (size_t)wid * 128 + lane * 2) = o;
}

// ---------------------------------------------------------------- launch ----
extern "C" void kernel_launch(void* const* d_in, const int* in_sizes, int n_in,
                              void* d_out, int out_size, void* d_ws, size_t ws_size,
                              hipStream_t stream) {
    const float* x = (const float*)d_in[0];
    const int* col1 = (const int*)d_in[2];
    const int* t1 = (const int*)d_in[3];
    const int* col2 = (const int*)d_in[5];
    const int* t2 = (const int*)d_in[6];
    const int* timep = (const int*)d_in[7];
    const int* intervalp = (const int*)d_in[8];
    const float* Ws1 = (const float*)d_in[9];
    const float* Wd1 = (const float*)d_in[10];
    const float* as1 = (const float*)d_in[11];
    const float* ad1 = (const float*)d_in[12];
    const float* b1 = (const float*)d_in[13];
    const float* g1 = (const float*)d_in[14];
    const float* beta1 = (const float*)d_in[15];
    const float* m1 = (const float*)d_in[16];
    const float* v1 = (const float*)d_in[17];
    const float* Ws2 = (const float*)d_in[18];
    const float* Wd2 = (const float*)d_in[19];
    const float* as2 = (const float*)d_in[20];
    const float* ad2 = (const float*)d_in[21];
    const float* b2 = (const float*)d_in[22];
    float* out = (float*)d_out;

    char* ws = (char*)d_ws;
    size_t off = 0;
    auto alloc = [&](size_t bytes) {
        size_t o = off;
        off += (bytes + 511) & ~(size_t)511;
        return o;
    };
    f16* hs = (f16*)(ws + alloc((size_t)N0C * 256 * 2));
    f16* h = (f16*)(ws + alloc((size_t)N1C * 256 * 2));
    f16* hs2 = (f16*)(ws + alloc((size_t)N1C * 128 * 2));
    float* a_s1 = (float*)(ws + alloc((size_t)N0C * 2 * 4));
    float* a_d1 = (float*)(ws + alloc((size_t)N1C * 2 * 4));
    float* a_s2 = (float*)(ws + alloc((size_t)N1C * 4));
    float* a_d2 = (float*)(ws + alloc((size_t)N2C * 4));
    f16* bfl1 = (f16*)(ws + alloc((size_t)73728 * 2));
    f16* bfl2 = (f16*)(ws + alloc((size_t)40960 * 2));
    float* e1 = (float*)(ws + alloc(1024 * 4));
    float* e2 = (float*)(ws + alloc(512 * 4));
    float* bns = (float*)(ws + alloc(256 * 4));
    float* bnt = (float*)(ws + alloc(256 * 4));

    prep1_kernel<<<256, 64, 0, stream>>>(Ws1, Wd1, as1, ad1, Ws2, Wd2, as2, ad2,
                                         b1, g1, beta1, m1, v1, e1, e2, bns, bnt);
    prep2_kernel<<<448, 256, 0, stream>>>(Ws1, Ws2, e1, e2, bfl1, bfl2);
    gemm1_kernel<<<(N0C + 127) / 128, 512, 0, stream>>>(x, bfl1, hs, a_s1, a_d1);
    agg1_kernel<<<N1C / 4, 256, 0, stream>>>(col1, t1, timep, intervalp,
                                             a_s1, a_d1, hs, bns, bnt, h);
    gemm2_kernel<<<(N1C + 127) / 128, 512, 0, stream>>>(h, bfl2, hs2, a_s2, a_d2);
    agg2_kernel<<<N2C / 4, 256, 0, stream>>>(col2, t2, timep, intervalp,
                                             a_s2, a_d2, hs2, b2, out);
}